// Round 1
// baseline (867.394 us; speedup 1.0000x reference)
//
#include <hip/hip_runtime.h>

// ---------- types ----------
typedef __attribute__((ext_vector_type(8))) short short8;   // 8 x bf16
typedef __attribute__((ext_vector_type(4))) short short4v;  // 4 x bf16
typedef __attribute__((ext_vector_type(4))) float float4v;

#define MFMA16(a, b, c) __builtin_amdgcn_mfma_f32_16x16x32_bf16((a), (b), (c), 0, 0, 0)

__device__ __forceinline__ short f2bf(float f) {  // RNE fp32 -> bf16
  unsigned u = __float_as_uint(f);
  u += 0x7fffu + ((u >> 16) & 1u);
  return (short)(u >> 16);
}

// ---------- fp32 -> bf16 cast ----------
__global__ __launch_bounds__(256) void castk(const float* __restrict__ in,
                                             short* __restrict__ out, int n4) {
  int i = blockIdx.x * 256 + threadIdx.x;
  if (i >= n4) return;
  float4v f = ((const float4v*)in)[i];
  short4v o;
  o[0] = f2bf(f[0]); o[1] = f2bf(f[1]); o[2] = f2bf(f[2]); o[3] = f2bf(f[3]);
  ((short4v*)out)[i] = o;
}

// ---------- generic MFMA GEMM: out[m, ocol+n] = A(M,K) @ W(N,K)^T + bias ----------
// block = 4 waves; wave w does rows [bm+16w, bm+16w+16), block cols [bn, bn+64)
// ROPE: apply reference's 768-wide rope to output columns (col index == rope index)
template <int ROPE, int OUTF32>
__global__ __launch_bounds__(256) void gemm_mfma(
    const short* __restrict__ A, int lda, const short* __restrict__ W, int ldw,
    const float* __restrict__ bias, float* __restrict__ outf,
    short* __restrict__ outb, int ldo, int ocol, int K,
    const int* __restrict__ pos, int smask) {
  int w = threadIdx.x >> 6, lane = threadIdx.x & 63;
  int quad = lane >> 4, l16 = lane & 15;
  int bm = blockIdx.y * 64, bn = blockIdx.x * 64;

  const short* Arow = A + (size_t)(bm + w * 16 + l16) * lda + quad * 8;
  const short* W0 = W + (size_t)(bn + l16) * ldw + quad * 8;

  float4v acc[4];
  float4v z = {0.f, 0.f, 0.f, 0.f};
  acc[0] = z; acc[1] = z; acc[2] = z; acc[3] = z;

#pragma unroll 4
  for (int k = 0; k < K; k += 32) {
    short8 a = *(const short8*)(Arow + k);
#pragma unroll
    for (int nt = 0; nt < 4; nt++) {
      short8 bfrag = *(const short8*)(W0 + (size_t)nt * 16 * ldw + k);
      acc[nt] = MFMA16(a, bfrag, acc[nt]);
    }
  }

#pragma unroll
  for (int nt = 0; nt < 4; nt++) {
    int col = bn + nt * 16 + l16;
    float bv = bias[col];
    float f = 0.f;
    if (ROPE)  // inv_freq = theta^(-(2i)/768), i = col>>1 ; theta=1e4, log2=13.2877...
      f = exp2f((float)(col & ~1) * (-13.287712379549449f / 768.0f));
#pragma unroll
    for (int r = 0; r < 4; r++) {
      int row = bm + w * 16 + quad * 4 + r;
      float v = acc[nt][r] + bv;
      float res;
      if (ROPE) {
        float pv = __shfl_xor(v, 1, 64);  // partner column (col^1), held by lane^1
        float ang = (float)pos[row & smask] * f;
        float sn, cs;
        sincosf(ang, &sn, &cs);
        res = (col & 1) ? (pv * sn + v * cs) : (v * cs - pv * sn);
      } else {
        res = v;
      }
      if (OUTF32)
        outf[(size_t)row * ldo + ocol + col] = res;
      else
        outb[(size_t)row * ldo + ocol + col] = f2bf(res);
    }
  }
}

// ---------- causal flash attention ----------
// grid (S/64, H, B), 256 threads. Q/K/V/O are (B*S, 1536) bf16, head h at cols h*128.
__global__ __launch_bounds__(256) void mla_attn(const short* __restrict__ Q,
                                                const short* __restrict__ K,
                                                const short* __restrict__ V,
                                                short* __restrict__ O) {
  const int ld = 1536;
  const int SEQ = 2048;
  int qt = blockIdx.x * 64;
  int h = blockIdx.y, b = blockIdx.z;
  int tid = threadIdx.x;
  int w = tid >> 6, lane = tid & 63, quad = lane >> 4, l16 = lane & 15;

  __shared__ short Kl[32][136];   // K tile, +8 pad: 2-way max on b128 reads
  __shared__ short Vt[128][40];   // V^T tile, XOR row swizzle, pad 40
  __shared__ short Pl[4][16][40]; // per-wave P staging (C-layout -> A-layout)

  const short* Qb = Q + ((size_t)b * SEQ) * ld + h * 128;
  const short* Kb = K + ((size_t)b * SEQ) * ld + h * 128;
  const short* Vb = V + ((size_t)b * SEQ) * ld + h * 128;

  int qrow = qt + w * 16 + l16;
  short8 qf[4];
#pragma unroll
  for (int c = 0; c < 4; c++)
    qf[c] = *(const short8*)(Qb + (size_t)qrow * ld + c * 32 + quad * 8);

  float4v oacc[8];
  float4v z = {0.f, 0.f, 0.f, 0.f};
#pragma unroll
  for (int n = 0; n < 8; n++) oacc[n] = z;
  float m_i[4] = {-1e30f, -1e30f, -1e30f, -1e30f};
  float l_i[4] = {0.f, 0.f, 0.f, 0.f};
  const float scale = 0.08838834764831845f;  // 1/sqrt(128)

  int krow = tid >> 3;         // 0..31
  int kcol = (tid & 7) * 16;   // 0..112

  for (int kt = 0; kt < qt + 64; kt += 32) {
    // ---- stage K (row-major) and V (transposed, swizzled) ----
    const short* ks = Kb + (size_t)(kt + krow) * ld + kcol;
    short8 k0 = *(const short8*)ks;
    short8 k1 = *(const short8*)(ks + 8);
    *(short8*)&Kl[krow][kcol] = k0;
    *(short8*)&Kl[krow][kcol + 8] = k1;
    const short* vs = Vb + (size_t)(kt + krow) * ld + kcol;
    short8 v0 = *(const short8*)vs;
    short8 v1 = *(const short8*)(vs + 8);
#pragma unroll
    for (int j = 0; j < 8; j++) {
      int n0 = kcol + j;
      Vt[n0 ^ ((n0 >> 4) << 1)][krow] = v0[j];
      int n1 = kcol + 8 + j;
      Vt[n1 ^ ((n1 >> 4) << 1)][krow] = v1[j];
    }
    __syncthreads();

    // ---- S = Q K^T (16 q-rows x 32 keys per wave) ----
    float4v s0 = z, s1 = z;
#pragma unroll
    for (int c = 0; c < 4; c++) {
      short8 b0 = *(const short8*)&Kl[l16][c * 32 + quad * 8];
      short8 b1 = *(const short8*)&Kl[16 + l16][c * 32 + quad * 8];
      s0 = MFMA16(qf[c], b0, s0);
      s1 = MFMA16(qf[c], b1, s1);
    }

    // ---- online softmax (rows quad*4+r, cols l16 / 16+l16) ----
#pragma unroll
    for (int r = 0; r < 4; r++) {
      int qr = qt + w * 16 + quad * 4 + r;
      float v0s = s0[r] * scale, v1s = s1[r] * scale;
      if (kt + l16 > qr) v0s = -1e30f;
      if (kt + 16 + l16 > qr) v1s = -1e30f;
      float mm = fmaxf(v0s, v1s);
      mm = fmaxf(mm, __shfl_xor(mm, 1, 64));
      mm = fmaxf(mm, __shfl_xor(mm, 2, 64));
      mm = fmaxf(mm, __shfl_xor(mm, 4, 64));
      mm = fmaxf(mm, __shfl_xor(mm, 8, 64));
      float mnew = fmaxf(m_i[r], mm);
      float alpha = __expf(m_i[r] - mnew);
      float p0 = __expf(v0s - mnew);
      float p1 = __expf(v1s - mnew);
      float ps = p0 + p1;
      ps += __shfl_xor(ps, 1, 64);
      ps += __shfl_xor(ps, 2, 64);
      ps += __shfl_xor(ps, 4, 64);
      ps += __shfl_xor(ps, 8, 64);
      l_i[r] = l_i[r] * alpha + ps;
      m_i[r] = mnew;
#pragma unroll
      for (int n = 0; n < 8; n++) oacc[n][r] *= alpha;
      Pl[w][quad * 4 + r][l16] = f2bf(p0);
      Pl[w][quad * 4 + r][16 + l16] = f2bf(p1);
    }

    // ---- O += P V (per-wave Pl round trip; wave-local, no barrier needed) ----
    short8 pf = *(const short8*)&Pl[w][l16][quad * 8];
#pragma unroll
    for (int nt = 0; nt < 8; nt++) {
      int n = nt * 16 + l16;
      short8 bv = *(const short8*)&Vt[n ^ ((n >> 4) << 1)][quad * 8];
      oacc[nt] = MFMA16(pf, bv, oacc[nt]);
    }
    __syncthreads();
  }

  short* Ob = O + ((size_t)b * SEQ) * ld + h * 128;
  float inv[4];
#pragma unroll
  for (int r = 0; r < 4; r++) inv[r] = 1.0f / l_i[r];
#pragma unroll
  for (int nt = 0; nt < 8; nt++) {
#pragma unroll
    for (int r = 0; r < 4; r++) {
      int row = qt + w * 16 + quad * 4 + r;
      Ob[(size_t)row * ld + nt * 16 + l16] = f2bf(oacc[nt][r] * inv[r]);
    }
  }
}

// ---------- launcher ----------
extern "C" void kernel_launch(void* const* d_in, const int* in_sizes, int n_in,
                              void* d_out, int out_size, void* d_ws, size_t ws_size,
                              hipStream_t stream) {
  const int B = 4, S = 2048, DM = 768, DL = 128, HD = 1536;  // HD = H*128
  const int M = B * S;  // 8192

  const float* x = (const float*)d_in[0];
  const int* pos = (const int*)d_in[1];
  const float* W_dkv = (const float*)d_in[2];
  const float* b_dkv = (const float*)d_in[3];
  const float* W_dq = (const float*)d_in[4];
  const float* b_dq = (const float*)d_in[5];
  const float* W_uk_nope = (const float*)d_in[6];
  const float* b_uk_nope = (const float*)d_in[7];
  const float* W_uv = (const float*)d_in[8];
  const float* b_uv = (const float*)d_in[9];
  const float* W_uq_nope = (const float*)d_in[10];
  const float* b_uq_nope = (const float*)d_in[11];
  const float* W_uq_rope = (const float*)d_in[12];
  const float* b_uq_rope = (const float*)d_in[13];
  const float* W_uk_rope = (const float*)d_in[14];
  const float* b_uk_rope = (const float*)d_in[15];
  const float* W_o = (const float*)d_in[16];
  const float* b_o = (const float*)d_in[17];

  char* p = (char*)d_ws;
  size_t off = 0;
  auto take = [&](size_t nelem) -> short* {
    short* r = (short*)(p + off);
    off += (nelem * 2 + 255) & ~(size_t)255;
    return r;
  };
  short* xb = take((size_t)M * DM);
  short* Wdkv = take(DL * DM);
  short* Wdq = take(DL * DM);
  short* Wuknope = take(768 * DL);
  short* Wuv = take(1536 * DL);
  short* Wuqnope = take(768 * DL);
  short* Wuqrope = take(768 * DL);
  short* Wukrope = take(768 * DM);
  short* Wo = take(768 * 1536);
  short* Cq = take((size_t)M * DL);
  short* Ckv = take((size_t)M * DL);
  short* Qm = take((size_t)M * HD);
  short* Km = take((size_t)M * HD);
  short* Vm = take((size_t)M * HD);
  short* Om = take((size_t)M * HD);
  if (off > ws_size) return;  // workspace too small: clean wrong-answer signal

  auto cast = [&](const float* in, short* out, int n) {
    castk<<<dim3((n / 4 + 255) / 256), dim3(256), 0, stream>>>(in, out, n / 4);
  };
  cast(x, xb, M * DM);
  cast(W_dkv, Wdkv, DL * DM);
  cast(W_dq, Wdq, DL * DM);
  cast(W_uk_nope, Wuknope, 768 * DL);
  cast(W_uv, Wuv, 1536 * DL);
  cast(W_uq_nope, Wuqnope, 768 * DL);
  cast(W_uq_rope, Wuqrope, 768 * DL);
  cast(W_uk_rope, Wukrope, 768 * DM);
  cast(W_o, Wo, 768 * 1536);

  const int smask = S - 1;
  // C_q, C_kv
  gemm_mfma<0, 0><<<dim3(DL / 64, M / 64), dim3(256), 0, stream>>>(
      xb, DM, Wdq, DM, b_dq, nullptr, Cq, DL, 0, DM, pos, smask);
  gemm_mfma<0, 0><<<dim3(DL / 64, M / 64), dim3(256), 0, stream>>>(
      xb, DM, Wdkv, DM, b_dkv, nullptr, Ckv, DL, 0, DM, pos, smask);
  // Q = [q_nope | rope(q_rope)]
  gemm_mfma<0, 0><<<dim3(768 / 64, M / 64), dim3(256), 0, stream>>>(
      Cq, DL, Wuqnope, DL, b_uq_nope, nullptr, Qm, HD, 0, DL, pos, smask);
  gemm_mfma<1, 0><<<dim3(768 / 64, M / 64), dim3(256), 0, stream>>>(
      Cq, DL, Wuqrope, DL, b_uq_rope, nullptr, Qm, HD, 768, DL, pos, smask);
  // K = [k_nope | rope(k_rope)]
  gemm_mfma<0, 0><<<dim3(768 / 64, M / 64), dim3(256), 0, stream>>>(
      Ckv, DL, Wuknope, DL, b_uk_nope, nullptr, Km, HD, 0, DL, pos, smask);
  gemm_mfma<1, 0><<<dim3(768 / 64, M / 64), dim3(256), 0, stream>>>(
      xb, DM, Wukrope, DM, b_uk_rope, nullptr, Km, HD, 768, DM, pos, smask);
  // V
  gemm_mfma<0, 0><<<dim3(1536 / 64, M / 64), dim3(256), 0, stream>>>(
      Ckv, DL, Wuv, DL, b_uv, nullptr, Vm, HD, 0, DL, pos, smask);
  // attention
  mla_attn<<<dim3(S / 64, 12, B), dim3(256), 0, stream>>>(Qm, Km, Vm, Om);
  // out = O @ W_o^T + b_o  (fp32)
  gemm_mfma<0, 1><<<dim3(768 / 64, M / 64), dim3(256), 0, stream>>>(
      Om, HD, Wo, HD, b_o, (float*)d_out, nullptr, 768, 0, HD, pos, smask);
}